// Round 7
// baseline (454.686 us; speedup 1.0000x reference)
//
#include <hip/hip_runtime.h>
#include <hip/hip_bf16.h>

#define NB 64
#define NU 64
#define NT 512
#define NH 8
#define KNN 9
#define NEGV -1000000000.0f

// =====================================================================
// Kernel A: one block per (b,u), 512 threads. Thread t owns task t
// (te/tk in registers). Masked softmax over 512 tasks via wave shfl
// butterflies + LDS partial combine. Thread 0 writes 8 f32 outputs.
// =====================================================================
__global__ void __launch_bounds__(512) k_usv(
    const float* __restrict__ usv_f, const float* __restrict__ task_f,
    const int* __restrict__ adj,
    const float* __restrict__ W_usv, const float* __restrict__ b_usv,
    const float* __restrict__ W_task, const float* __restrict__ b_task,
    const float* __restrict__ W_au, const float* __restrict__ b_au,
    const float* __restrict__ W_Q, const float* __restrict__ b_Q,
    const float* __restrict__ W_K, const float* __restrict__ b_K,
    float* __restrict__ out_usv)
{
    __shared__ float s_max[8];
    __shared__ float s_sum[8];
    __shared__ float s_agg[8][NH];

    const int b = blockIdx.x >> 6;     // blockIdx.x = b*NU + u
    const int u = blockIdx.x & 63;
    const int t = threadIdx.x;         // task index, 0..511
    const int lane = t & 63, wv = t >> 6;

    // --- every thread: usv_embed (ue) and uq (q), redundant broadcast ---
    float ue[NH], q[NH];
    {
        float f0 = usv_f[(b * NU + u) * 4 + 0];
        float f1 = usv_f[(b * NU + u) * 4 + 1];
        float f2 = usv_f[(b * NU + u) * 4 + 2];
        float f3 = usv_f[(b * NU + u) * 4 + 3];
        #pragma unroll
        for (int h = 0; h < NH; ++h)
            ue[h] = b_usv[h] + f0 * W_usv[0 * NH + h] + f1 * W_usv[1 * NH + h]
                             + f2 * W_usv[2 * NH + h] + f3 * W_usv[3 * NH + h];
        #pragma unroll
        for (int h = 0; h < NH; ++h) {
            float a = b_Q[h];
            #pragma unroll
            for (int j = 0; j < NH; ++j) a += ue[j] * W_Q[j * NH + h];
            q[h] = a;
        }
    }

    // --- own task t: task_embed (te) and tk, in registers ---
    float te[NH], tk[NH];
    {
        float f[5];
        #pragma unroll
        for (int j = 0; j < 5; ++j) f[j] = task_f[(b * NT + t) * 5 + j];
        #pragma unroll
        for (int h = 0; h < NH; ++h) {
            float a = b_task[h];
            #pragma unroll
            for (int j = 0; j < 5; ++j) a += f[j] * W_task[j * NH + h];
            te[h] = a;
        }
        #pragma unroll
        for (int h = 0; h < NH; ++h) {
            float a = b_K[h];
            #pragma unroll
            for (int j = 0; j < NH; ++j) a += te[j] * W_K[j * NH + h];
            tk[h] = a;
        }
    }

    // --- score s[b,u,t] ---
    float sc = b_au[0];
    #pragma unroll
    for (int h = 0; h < NH; ++h) sc += tanhf(q[h] + tk[h]) * W_au[h];
    if (adj[(b * NU + u) * NT + t] == 0) sc = NEGV;

    // --- block max ---
    float m = sc;
    #pragma unroll
    for (int o = 32; o; o >>= 1) m = fmaxf(m, __shfl_xor(m, o));
    if (lane == 0) s_max[wv] = m;
    __syncthreads();
    float M = s_max[0];
    for (int w = 1; w < 8; ++w) M = fmaxf(M, s_max[w]);

    // --- exp + block sum + weighted agg partials ---
    float p = expf(sc - M);
    float ps = p;
    #pragma unroll
    for (int o = 32; o; o >>= 1) ps += __shfl_xor(ps, o);
    float ag[NH];
    #pragma unroll
    for (int h = 0; h < NH; ++h) {
        float v = p * te[h];
        #pragma unroll
        for (int o = 32; o; o >>= 1) v += __shfl_xor(v, o);
        ag[h] = v;
    }
    if (lane == 0) {
        s_sum[wv] = ps;
        #pragma unroll
        for (int h = 0; h < NH; ++h) s_agg[wv][h] = ag[h];
    }
    __syncthreads();

    // --- thread 0: combine, finish, write (f32!) ---
    if (t == 0) {
        float PS = 0.f;
        for (int w = 0; w < 8; ++w) PS += s_sum[w];
        float inv = 1.f / PS;
        #pragma unroll
        for (int h = 0; h < NH; ++h) {
            float A = 0.f;
            for (int w = 0; w < 8; ++w) A += s_agg[w][h];
            float sig = 1.f / (1.f + expf(-q[h]));
            float x = sig * ue[h] + A * inv;
            float upd = x > 0.f ? x : expm1f(x);
            out_usv[(b * NU + u) * NH + h] = upd;
        }
    }
}

// =====================================================================
// Kernel B: task side. grid = NB*8 blocks, 64 threads (t = tile*64+tid).
// Stages task embed/tK in LDS; reads usv_updated (f32) from out_usv
// (written by kernel A on the same stream); recomputes uk on the fly.
// kNN top-9 with lexicographic (dist, idx) ties == jax.lax.top_k.
// =====================================================================
__global__ void __launch_bounds__(64) k_task(
    const float* __restrict__ task_f,
    const float* __restrict__ W_task, const float* __restrict__ b_task,
    const float* __restrict__ W_K, const float* __restrict__ b_K,
    const float* __restrict__ W_V, const float* __restrict__ b_V,
    const float* __restrict__ W_Q, const float* __restrict__ b_Q,
    const float* __restrict__ W_at, const float* __restrict__ b_at,
    const float* __restrict__ out_usv,
    float* __restrict__ out_task)
{
    __shared__ float sh_te[NT][NH + 1];
    __shared__ float sh_tk[NT][NH + 1];
    __shared__ float cx[NT], cy[NT];
    __shared__ float sh_uk[NU][NH];
    __shared__ float sh_up[NU][NH];

    int b    = blockIdx.x >> 3;
    int tile = blockIdx.x & 7;
    int tid  = threadIdx.x;
    int t    = tile * 64 + tid;

    // --- cooperative compute of embed/tK + coords for all 512 tasks ---
    for (int i = tid; i < NT; i += 64) {
        float f[5];
        #pragma unroll
        for (int j = 0; j < 5; ++j) f[j] = task_f[(b * NT + i) * 5 + j];
        cx[i] = f[0]; cy[i] = f[1];
        float e[NH];
        #pragma unroll
        for (int h = 0; h < NH; ++h) {
            float a = b_task[h];
            #pragma unroll
            for (int j = 0; j < 5; ++j) a += f[j] * W_task[j * NH + h];
            e[h] = a;
            sh_te[i][h] = a;
        }
        #pragma unroll
        for (int h = 0; h < NH; ++h) {
            float a = b_K[h];
            #pragma unroll
            for (int j = 0; j < NH; ++j) a += e[j] * W_K[j * NH + h];
            sh_tk[i][h] = a;
        }
    }
    // --- usv_updated (f32, from out_usv) + uk recompute, one u/thread ---
    {
        int u = tid;
        float up[NH];
        #pragma unroll
        for (int h = 0; h < NH; ++h) {
            up[h] = out_usv[(b * NU + u) * NH + h];
            sh_up[u][h] = up[h];
        }
        #pragma unroll
        for (int h = 0; h < NH; ++h) {
            float a = b_Q[h];
            #pragma unroll
            for (int j = 0; j < NH; ++j) a += up[j] * W_Q[j * NH + h];
            sh_uk[u][h] = a;
        }
    }
    __syncthreads();

    // tq = task_embed @ W_V + b_V for own t
    float tq[NH];
    #pragma unroll
    for (int h = 0; h < NH; ++h) {
        float a = b_V[h];
        #pragma unroll
        for (int j = 0; j < NH; ++j) a += sh_te[t][j] * W_V[j * NH + h];
        tq[h] = a;
    }
    float wat[NH];
    #pragma unroll
    for (int h = 0; h < NH; ++h) wat[h] = W_at[h];
    float bat = b_at[0];

    // --- top-9 nearest by sqrtf distance, lex (d, idx) ties (== top_k) ---
    float mx = cx[t], my = cy[t];
    float bd[KNN]; int bi[KNN];
    #pragma unroll
    for (int j = 0; j < KNN; ++j) { bd[j] = 3.0e38f; bi[j] = 0x7fffffff; }
    for (int s = 0; s < NT; ++s) {
        float dx = mx - cx[s], dy = my - cy[s];
        float d = sqrtf(dx * dx + dy * dy);
        float maxd = bd[0]; int maxj = 0; int maxsi = bi[0];
        #pragma unroll
        for (int j = 1; j < KNN; ++j) {
            bool g = (bd[j] > maxd) || (bd[j] == maxd && bi[j] > maxsi);
            if (g) { maxd = bd[j]; maxj = j; maxsi = bi[j]; }
        }
        if (d < maxd || (d == maxd && s < maxsi)) {
            #pragma unroll
            for (int j = 0; j < KNN; ++j) if (j == maxj) { bd[j] = d; bi[j] = s; }
        }
    }

    // --- ts over the 9 neighbors, softmax, agg_tasks ---
    float v9[KNN], vmax = -3.0e38f;
    #pragma unroll
    for (int j = 0; j < KNN; ++j) {
        int s = bi[j];
        float a = bat;
        #pragma unroll
        for (int h = 0; h < NH; ++h) a += tanhf(tq[h] + sh_tk[s][h]) * wat[h];
        v9[j] = a;
        vmax = fmaxf(vmax, a);
    }
    float ssum = 0.f, aggT[NH];
    #pragma unroll
    for (int h = 0; h < NH; ++h) aggT[h] = 0.f;
    #pragma unroll
    for (int j = 0; j < KNN; ++j) {
        float p = expf(v9[j] - vmax);
        ssum += p;
        int s = bi[j];
        #pragma unroll
        for (int h = 0; h < NH; ++h) aggT[h] += p * sh_te[s][h];
    }
    float invT = 1.f / ssum;

    // --- online softmax over 64 u's (tu, axis=u), agg_usv ---
    float um = -3.0e38f, us = 0.f, aggU[NH];
    #pragma unroll
    for (int h = 0; h < NH; ++h) aggU[h] = 0.f;
    for (int u = 0; u < NU; ++u) {
        float a = bat;
        #pragma unroll
        for (int h = 0; h < NH; ++h) a += tanhf(sh_uk[u][h] + tq[h]) * wat[h];
        if (a > um) {
            float r = expf(um - a);
            us *= r;
            #pragma unroll
            for (int h = 0; h < NH; ++h) aggU[h] *= r;
            um = a;
        }
        float p = expf(a - um);
        us += p;
        #pragma unroll
        for (int h = 0; h < NH; ++h) aggU[h] += p * sh_up[u][h];
    }
    float invU = 1.f / us;

    // --- task_updated (f32!) ---
    #pragma unroll
    for (int h = 0; h < NH; ++h) {
        float sig = 1.f / (1.f + expf(-tq[h]));
        float x = sig * sh_te[t][h] + aggT[h] * invT + aggU[h] * invU;
        float r = x > 0.f ? x : expm1f(x);
        out_task[(b * NT + t) * NH + h] = r;
    }
}

extern "C" void kernel_launch(void* const* d_in, const int* in_sizes, int n_in,
                              void* d_out, int out_size, void* d_ws, size_t ws_size,
                              hipStream_t stream)
{
    const float* usv_f  = (const float*)d_in[0];
    const float* task_f = (const float*)d_in[1];
    const int*   adj    = (const int*)  d_in[2];
    // d_in[3] edge_features: unused by the reference
    const float* W_usv  = (const float*)d_in[4];
    const float* b_usv  = (const float*)d_in[5];
    const float* W_task = (const float*)d_in[6];
    const float* b_task = (const float*)d_in[7];
    const float* W_au   = (const float*)d_in[8];
    const float* b_au   = (const float*)d_in[9];
    const float* W_at   = (const float*)d_in[10];
    const float* b_at   = (const float*)d_in[11];
    const float* W_Q    = (const float*)d_in[12];
    const float* b_Q    = (const float*)d_in[13];
    const float* W_K    = (const float*)d_in[14];
    const float* b_K    = (const float*)d_in[15];
    const float* W_V    = (const float*)d_in[16];
    const float* b_V    = (const float*)d_in[17];

    float* out_usv  = (float*)d_out;               // f32 output!
    float* out_task = out_usv + NB * NU * NH;

    hipLaunchKernelGGL(k_usv, dim3(NB * NU), dim3(512), 0, stream,
                       usv_f, task_f, adj,
                       W_usv, b_usv, W_task, b_task, W_au, b_au,
                       W_Q, b_Q, W_K, b_K, out_usv);
    hipLaunchKernelGGL(k_task, dim3(NB * 8), dim3(64), 0, stream,
                       task_f, W_task, b_task, W_K, b_K, W_V, b_V,
                       W_Q, b_Q, W_at, b_at, out_usv, out_task);
}

// Round 8
// 274.563 us; speedup vs baseline: 1.6560x; 1.6560x over previous
//
#include <hip/hip_runtime.h>
#include <hip/hip_bf16.h>

#define NB 64
#define NU 64
#define NT 512
#define NH 8
#define KNN 9
#define NEGV -1000000000.0f

// fast tanh via hardware exp: exact at saturation (x->+inf: 1, x->-inf: -1)
__device__ __forceinline__ float ft(float x) {
    return 1.f - 2.f / (__expf(2.f * x) + 1.f);
}

// =====================================================================
// Kernel A: one block per (b,u), 512 threads. Thread t owns task t
// (te/tk in registers). Masked softmax over 512 tasks via wave shfl
// butterflies + LDS partial combine. Thread 0 writes 8 f32 outputs.
// (structure identical to the round-7 passing version; tanhf->ft,
//  expf->__expf only)
// =====================================================================
__global__ void __launch_bounds__(512) k_usv(
    const float* __restrict__ usv_f, const float* __restrict__ task_f,
    const int* __restrict__ adj,
    const float* __restrict__ W_usv, const float* __restrict__ b_usv,
    const float* __restrict__ W_task, const float* __restrict__ b_task,
    const float* __restrict__ W_au, const float* __restrict__ b_au,
    const float* __restrict__ W_Q, const float* __restrict__ b_Q,
    const float* __restrict__ W_K, const float* __restrict__ b_K,
    float* __restrict__ out_usv)
{
    __shared__ float s_max[8];
    __shared__ float s_sum[8];
    __shared__ float s_agg[8][NH];

    const int b = blockIdx.x >> 6;     // blockIdx.x = b*NU + u
    const int u = blockIdx.x & 63;
    const int t = threadIdx.x;         // task index, 0..511
    const int lane = t & 63, wv = t >> 6;

    float ue[NH], q[NH];
    {
        float f0 = usv_f[(b * NU + u) * 4 + 0];
        float f1 = usv_f[(b * NU + u) * 4 + 1];
        float f2 = usv_f[(b * NU + u) * 4 + 2];
        float f3 = usv_f[(b * NU + u) * 4 + 3];
        #pragma unroll
        for (int h = 0; h < NH; ++h)
            ue[h] = b_usv[h] + f0 * W_usv[0 * NH + h] + f1 * W_usv[1 * NH + h]
                             + f2 * W_usv[2 * NH + h] + f3 * W_usv[3 * NH + h];
        #pragma unroll
        for (int h = 0; h < NH; ++h) {
            float a = b_Q[h];
            #pragma unroll
            for (int j = 0; j < NH; ++j) a += ue[j] * W_Q[j * NH + h];
            q[h] = a;
        }
    }

    float te[NH], tk[NH];
    {
        float f[5];
        #pragma unroll
        for (int j = 0; j < 5; ++j) f[j] = task_f[(b * NT + t) * 5 + j];
        #pragma unroll
        for (int h = 0; h < NH; ++h) {
            float a = b_task[h];
            #pragma unroll
            for (int j = 0; j < 5; ++j) a += f[j] * W_task[j * NH + h];
            te[h] = a;
        }
        #pragma unroll
        for (int h = 0; h < NH; ++h) {
            float a = b_K[h];
            #pragma unroll
            for (int j = 0; j < NH; ++j) a += te[j] * W_K[j * NH + h];
            tk[h] = a;
        }
    }

    float sc = b_au[0];
    #pragma unroll
    for (int h = 0; h < NH; ++h) sc += ft(q[h] + tk[h]) * W_au[h];
    if (adj[(b * NU + u) * NT + t] == 0) sc = NEGV;

    float m = sc;
    #pragma unroll
    for (int o = 32; o; o >>= 1) m = fmaxf(m, __shfl_xor(m, o));
    if (lane == 0) s_max[wv] = m;
    __syncthreads();
    float M = s_max[0];
    for (int w = 1; w < 8; ++w) M = fmaxf(M, s_max[w]);

    float p = __expf(sc - M);
    float ps = p;
    #pragma unroll
    for (int o = 32; o; o >>= 1) ps += __shfl_xor(ps, o);
    float ag[NH];
    #pragma unroll
    for (int h = 0; h < NH; ++h) {
        float v = p * te[h];
        #pragma unroll
        for (int o = 32; o; o >>= 1) v += __shfl_xor(v, o);
        ag[h] = v;
    }
    if (lane == 0) {
        s_sum[wv] = ps;
        #pragma unroll
        for (int h = 0; h < NH; ++h) s_agg[wv][h] = ag[h];
    }
    __syncthreads();

    if (t == 0) {
        float PS = 0.f;
        for (int w = 0; w < 8; ++w) PS += s_sum[w];
        float inv = 1.f / PS;
        #pragma unroll
        for (int h = 0; h < NH; ++h) {
            float A = 0.f;
            for (int w = 0; w < 8; ++w) A += s_agg[w][h];
            float sig = 1.f / (1.f + __expf(-q[h]));
            float x = sig * ue[h] + A * inv;
            float upd = x > 0.f ? x : __expf(x) - 1.f;
            out_usv[(b * NU + u) * NH + h] = upd;
        }
    }
}

// =====================================================================
// Kernel B (wave-per-task): block = 512 threads = 8 waves; wave w of
// block g handles (b,t) with gw = g*8+w, b = gw>>9, t = gw&511.
// Phase 1: 9-round butterfly lex-min kNN (lanes hold 8 candidates each).
// Phase 2: 9-neighbor tanh attention on lanes 0-8, 16-lane butterflies.
// Phase 3: u-softmax, lane = u, 64-lane butterflies.
// No LDS, no __syncthreads; all register + shfl.
// =====================================================================
__global__ void __launch_bounds__(512) k_task2(
    const float* __restrict__ task_f,
    const float* __restrict__ W_task, const float* __restrict__ b_task,
    const float* __restrict__ W_K, const float* __restrict__ b_K,
    const float* __restrict__ W_V, const float* __restrict__ b_V,
    const float* __restrict__ W_Q, const float* __restrict__ b_Q,
    const float* __restrict__ W_at, const float* __restrict__ b_at,
    const float* __restrict__ out_usv,
    float* __restrict__ out_task)
{
    const int wid  = threadIdx.x >> 6;
    const int lane = threadIdx.x & 63;
    const int gw   = blockIdx.x * 8 + wid;   // 0 .. NB*NT-1
    const int b    = gw >> 9;
    const int t    = gw & 511;

    // --- load my 8 candidate coords (s = i*64 + lane) ---
    float cxl[8], cyl[8];
    #pragma unroll
    for (int i = 0; i < 8; ++i) {
        int s = i * 64 + lane;
        cxl[i] = task_f[(b * NT + s) * 5 + 0];
        cyl[i] = task_f[(b * NT + s) * 5 + 1];
    }
    // own coords broadcast from owner lane
    float mx = __shfl(cxl[t >> 6], t & 63);
    float my = __shfl(cyl[t >> 6], t & 63);

    float dl[8];
    #pragma unroll
    for (int i = 0; i < 8; ++i) {
        float dx = mx - cxl[i], dy = my - cyl[i];
        dl[i] = sqrtf(dx * dx + dy * dy);
    }

    // --- 9 rounds of wave-wide lex-min (d, idx) extraction ---
    unsigned msk = 0;
    int mynb = t;                       // lanes >= 9 keep safe default
    #pragma unroll
    for (int j = 0; j < KNN; ++j) {
        float bd = 3.0e38f; int bi_ = 0x7fffffff;
        #pragma unroll
        for (int i = 0; i < 8; ++i) {
            int si = i * 64 + lane;
            bool ok = !((msk >> i) & 1u);
            if (ok && (dl[i] < bd || (dl[i] == bd && si < bi_))) { bd = dl[i]; bi_ = si; }
        }
        #pragma unroll
        for (int o = 32; o; o >>= 1) {
            float d2 = __shfl_xor(bd, o);
            int   i2 = __shfl_xor(bi_, o);
            if (d2 < bd || (d2 == bd && i2 < bi_)) { bd = d2; bi_ = i2; }
        }
        if (lane == j) mynb = bi_;
        if ((bi_ & 63) == lane) msk |= 1u << (bi_ >> 6);
    }

    // --- own task embed + tq (all lanes, uniform) ---
    float te[NH], tq[NH];
    {
        float f[5];
        #pragma unroll
        for (int j = 0; j < 5; ++j) f[j] = task_f[(b * NT + t) * 5 + j];
        #pragma unroll
        for (int h = 0; h < NH; ++h) {
            float a = b_task[h];
            #pragma unroll
            for (int j = 0; j < 5; ++j) a += f[j] * W_task[j * NH + h];
            te[h] = a;
        }
        #pragma unroll
        for (int h = 0; h < NH; ++h) {
            float a = b_V[h];
            #pragma unroll
            for (int j = 0; j < NH; ++j) a += te[j] * W_V[j * NH + h];
            tq[h] = a;
        }
    }
    float wat[NH];
    #pragma unroll
    for (int h = 0; h < NH; ++h) wat[h] = W_at[h];
    float bat = b_at[0];

    // --- phase 2: neighbor scoring (lanes 0-8 meaningful) ---
    float tej[NH], sc2;
    {
        int s = mynb;
        float g[5];
        #pragma unroll
        for (int j = 0; j < 5; ++j) g[j] = task_f[(b * NT + s) * 5 + j];
        float tkj[NH];
        #pragma unroll
        for (int h = 0; h < NH; ++h) {
            float a = b_task[h];
            #pragma unroll
            for (int j = 0; j < 5; ++j) a += g[j] * W_task[j * NH + h];
            tej[h] = a;
        }
        #pragma unroll
        for (int h = 0; h < NH; ++h) {
            float a = b_K[h];
            #pragma unroll
            for (int j = 0; j < NH; ++j) a += tej[j] * W_K[j * NH + h];
            tkj[h] = a;
        }
        sc2 = bat;
        #pragma unroll
        for (int h = 0; h < NH; ++h) sc2 += ft(tq[h] + tkj[h]) * wat[h];
    }
    float a2 = (lane < KNN) ? sc2 : -3.0e38f;
    float vm = a2;
    #pragma unroll
    for (int o = 8; o; o >>= 1) vm = fmaxf(vm, __shfl_xor(vm, o));
    float p2 = (lane < KNN) ? __expf(a2 - vm) : 0.f;
    float ss = p2;
    #pragma unroll
    for (int o = 8; o; o >>= 1) ss += __shfl_xor(ss, o);
    float aggT[NH];
    #pragma unroll
    for (int h = 0; h < NH; ++h) {
        float v = p2 * tej[h];
        #pragma unroll
        for (int o = 8; o; o >>= 1) v += __shfl_xor(v, o);
        aggT[h] = v;
    }

    // --- phase 3: u-softmax, lane = u ---
    float up[NH], uk[NH];
    #pragma unroll
    for (int h = 0; h < NH; ++h) up[h] = out_usv[(b * NU + lane) * NH + h];
    #pragma unroll
    for (int h = 0; h < NH; ++h) {
        float a = b_Q[h];
        #pragma unroll
        for (int j = 0; j < NH; ++j) a += up[j] * W_Q[j * NH + h];
        uk[h] = a;
    }
    float au = bat;
    #pragma unroll
    for (int h = 0; h < NH; ++h) au += ft(uk[h] + tq[h]) * wat[h];
    float um = au;
    #pragma unroll
    for (int o = 32; o; o >>= 1) um = fmaxf(um, __shfl_xor(um, o));
    float pu = __expf(au - um);
    float su = pu;
    #pragma unroll
    for (int o = 32; o; o >>= 1) su += __shfl_xor(su, o);
    float aggU[NH];
    #pragma unroll
    for (int h = 0; h < NH; ++h) {
        float v = pu * up[h];
        #pragma unroll
        for (int o = 32; o; o >>= 1) v += __shfl_xor(v, o);
        aggU[h] = v;
    }

    // --- finalize on lanes 0-7 (h = lane); static-index selection ---
    float tqh = tq[0], teh = te[0], aT = aggT[0], aU = aggU[0];
    #pragma unroll
    for (int h = 1; h < NH; ++h)
        if (lane == h) { tqh = tq[h]; teh = te[h]; aT = aggT[h]; aU = aggU[h]; }
    if (lane < NH) {
        float invT = 1.f / ss, invU = 1.f / su;
        float sig = 1.f / (1.f + __expf(-tqh));
        float x = sig * teh + aT * invT + aU * invU;
        float r = x > 0.f ? x : __expf(x) - 1.f;
        out_task[(b * NT + t) * NH + lane] = r;
    }
}

extern "C" void kernel_launch(void* const* d_in, const int* in_sizes, int n_in,
                              void* d_out, int out_size, void* d_ws, size_t ws_size,
                              hipStream_t stream)
{
    const float* usv_f  = (const float*)d_in[0];
    const float* task_f = (const float*)d_in[1];
    const int*   adj    = (const int*)  d_in[2];
    // d_in[3] edge_features: unused by the reference
    const float* W_usv  = (const float*)d_in[4];
    const float* b_usv  = (const float*)d_in[5];
    const float* W_task = (const float*)d_in[6];
    const float* b_task = (const float*)d_in[7];
    const float* W_au   = (const float*)d_in[8];
    const float* b_au   = (const float*)d_in[9];
    const float* W_at   = (const float*)d_in[10];
    const float* b_at   = (const float*)d_in[11];
    const float* W_Q    = (const float*)d_in[12];
    const float* b_Q    = (const float*)d_in[13];
    const float* W_K    = (const float*)d_in[14];
    const float* b_K    = (const float*)d_in[15];
    const float* W_V    = (const float*)d_in[16];
    const float* b_V    = (const float*)d_in[17];

    float* out_usv  = (float*)d_out;
    float* out_task = out_usv + NB * NU * NH;

    hipLaunchKernelGGL(k_usv, dim3(NB * NU), dim3(512), 0, stream,
                       usv_f, task_f, adj,
                       W_usv, b_usv, W_task, b_task, W_au, b_au,
                       W_Q, b_Q, W_K, b_K, out_usv);
    hipLaunchKernelGGL(k_task2, dim3(NB * NT / 8), dim3(512), 0, stream,
                       task_f, W_task, b_task, W_K, b_K, W_V, b_V,
                       W_Q, b_Q, W_at, b_at, out_usv, out_task);
}

// Round 9
// 143.389 us; speedup vs baseline: 3.1710x; 1.9148x over previous
//
#include <hip/hip_runtime.h>
#include <hip/hip_bf16.h>

#define NB 64
#define NU 64
#define NT 512
#define NH 8
#define KNN 9
#define PAD 9
#define NEGV -1000000000.0f

// fast tanh via hardware exp: exact at saturation
__device__ __forceinline__ float ft(float x) {
    return 1.f - 2.f / (__expf(2.f * x) + 1.f);
}

// =====================================================================
// Kernel A: unchanged from round 8 (passing, ~16us).
// =====================================================================
__global__ void __launch_bounds__(512) k_usv(
    const float* __restrict__ usv_f, const float* __restrict__ task_f,
    const int* __restrict__ adj,
    const float* __restrict__ W_usv, const float* __restrict__ b_usv,
    const float* __restrict__ W_task, const float* __restrict__ b_task,
    const float* __restrict__ W_au, const float* __restrict__ b_au,
    const float* __restrict__ W_Q, const float* __restrict__ b_Q,
    const float* __restrict__ W_K, const float* __restrict__ b_K,
    float* __restrict__ out_usv)
{
    __shared__ float s_max[8];
    __shared__ float s_sum[8];
    __shared__ float s_agg[8][NH];

    const int b = blockIdx.x >> 6;
    const int u = blockIdx.x & 63;
    const int t = threadIdx.x;
    const int lane = t & 63, wv = t >> 6;

    float ue[NH], q[NH];
    {
        float f0 = usv_f[(b * NU + u) * 4 + 0];
        float f1 = usv_f[(b * NU + u) * 4 + 1];
        float f2 = usv_f[(b * NU + u) * 4 + 2];
        float f3 = usv_f[(b * NU + u) * 4 + 3];
        #pragma unroll
        for (int h = 0; h < NH; ++h)
            ue[h] = b_usv[h] + f0 * W_usv[0 * NH + h] + f1 * W_usv[1 * NH + h]
                             + f2 * W_usv[2 * NH + h] + f3 * W_usv[3 * NH + h];
        #pragma unroll
        for (int h = 0; h < NH; ++h) {
            float a = b_Q[h];
            #pragma unroll
            for (int j = 0; j < NH; ++j) a += ue[j] * W_Q[j * NH + h];
            q[h] = a;
        }
    }

    float te[NH], tk[NH];
    {
        float f[5];
        #pragma unroll
        for (int j = 0; j < 5; ++j) f[j] = task_f[(b * NT + t) * 5 + j];
        #pragma unroll
        for (int h = 0; h < NH; ++h) {
            float a = b_task[h];
            #pragma unroll
            for (int j = 0; j < 5; ++j) a += f[j] * W_task[j * NH + h];
            te[h] = a;
        }
        #pragma unroll
        for (int h = 0; h < NH; ++h) {
            float a = b_K[h];
            #pragma unroll
            for (int j = 0; j < NH; ++j) a += te[j] * W_K[j * NH + h];
            tk[h] = a;
        }
    }

    float sc = b_au[0];
    #pragma unroll
    for (int h = 0; h < NH; ++h) sc += ft(q[h] + tk[h]) * W_au[h];
    if (adj[(b * NU + u) * NT + t] == 0) sc = NEGV;

    float m = sc;
    #pragma unroll
    for (int o = 32; o; o >>= 1) m = fmaxf(m, __shfl_xor(m, o));
    if (lane == 0) s_max[wv] = m;
    __syncthreads();
    float M = s_max[0];
    for (int w = 1; w < 8; ++w) M = fmaxf(M, s_max[w]);

    float p = __expf(sc - M);
    float ps = p;
    #pragma unroll
    for (int o = 32; o; o >>= 1) ps += __shfl_xor(ps, o);
    float ag[NH];
    #pragma unroll
    for (int h = 0; h < NH; ++h) {
        float v = p * te[h];
        #pragma unroll
        for (int o = 32; o; o >>= 1) v += __shfl_xor(v, o);
        ag[h] = v;
    }
    if (lane == 0) {
        s_sum[wv] = ps;
        #pragma unroll
        for (int h = 0; h < NH; ++h) s_agg[wv][h] = ag[h];
    }
    __syncthreads();

    if (t == 0) {
        float PS = 0.f;
        for (int w = 0; w < 8; ++w) PS += s_sum[w];
        float inv = 1.f / PS;
        #pragma unroll
        for (int h = 0; h < NH; ++h) {
            float A = 0.f;
            for (int w = 0; w < 8; ++w) A += s_agg[w][h];
            float sig = 1.f / (1.f + __expf(-q[h]));
            float x = sig * ue[h] + A * inv;
            float upd = x > 0.f ? x : __expf(x) - 1.f;
            out_usv[(b * NU + u) * NH + h] = upd;
        }
    }
}

// =====================================================================
// Kernel B (LDS-staged wave-per-task): grid = NB*64 blocks (b, group of
// 8 tasks), 512 threads = 8 waves, wave = one task. Per-block staging:
// coords + te/tk for all 512 tasks, up/uk for 64 u's (coalesced loads,
// computed once). Phases identical to round 8, all reads from LDS.
// =====================================================================
__global__ void __launch_bounds__(512) k_task3(
    const float* __restrict__ task_f,
    const float* __restrict__ W_task, const float* __restrict__ b_task,
    const float* __restrict__ W_K, const float* __restrict__ b_K,
    const float* __restrict__ W_V, const float* __restrict__ b_V,
    const float* __restrict__ W_Q, const float* __restrict__ b_Q,
    const float* __restrict__ W_at, const float* __restrict__ b_at,
    const float* __restrict__ out_usv,
    float* __restrict__ out_task)
{
    __shared__ float s_cx[NT], s_cy[NT];
    __shared__ float s_te[NT][PAD];
    __shared__ float s_tk[NT][PAD];
    __shared__ float s_up[NU][PAD];
    __shared__ float s_uk[NU][PAD];

    const int b    = blockIdx.x >> 6;
    const int tile = blockIdx.x & 63;
    const int wid  = threadIdx.x >> 6;
    const int lane = threadIdx.x & 63;
    const int t    = tile * 8 + wid;     // this wave's task

    // --- staging: thread i computes te/tk/coords for task i ---
    {
        int i = threadIdx.x;
        float f[5];
        #pragma unroll
        for (int j = 0; j < 5; ++j) f[j] = task_f[(b * NT + i) * 5 + j];
        s_cx[i] = f[0]; s_cy[i] = f[1];
        float e[NH];
        #pragma unroll
        for (int h = 0; h < NH; ++h) {
            float a = b_task[h];
            #pragma unroll
            for (int j = 0; j < 5; ++j) a += f[j] * W_task[j * NH + h];
            e[h] = a;
            s_te[i][h] = a;
        }
        #pragma unroll
        for (int h = 0; h < NH; ++h) {
            float a = b_K[h];
            #pragma unroll
            for (int j = 0; j < NH; ++j) a += e[j] * W_K[j * NH + h];
            s_tk[i][h] = a;
        }
    }
    if (threadIdx.x < NU) {
        int u = threadIdx.x;
        float up[NH];
        #pragma unroll
        for (int h = 0; h < NH; ++h) {
            up[h] = out_usv[(b * NU + u) * NH + h];
            s_up[u][h] = up[h];
        }
        #pragma unroll
        for (int h = 0; h < NH; ++h) {
            float a = b_Q[h];
            #pragma unroll
            for (int j = 0; j < NH; ++j) a += up[j] * W_Q[j * NH + h];
            s_uk[u][h] = a;
        }
    }
    __syncthreads();

    // --- phase 1: dists from LDS, 9-round lex-min extraction ---
    float mx = s_cx[t], my = s_cy[t];
    float dl[8];
    #pragma unroll
    for (int i = 0; i < 8; ++i) {
        int s = i * 64 + lane;
        float dx = mx - s_cx[s], dy = my - s_cy[s];
        dl[i] = sqrtf(dx * dx + dy * dy);
    }
    unsigned msk = 0;
    int mynb = t;
    #pragma unroll
    for (int j = 0; j < KNN; ++j) {
        float bd = 3.0e38f; int bi_ = 0x7fffffff;
        #pragma unroll
        for (int i = 0; i < 8; ++i) {
            int si = i * 64 + lane;
            bool ok = !((msk >> i) & 1u);
            if (ok && (dl[i] < bd || (dl[i] == bd && si < bi_))) { bd = dl[i]; bi_ = si; }
        }
        #pragma unroll
        for (int o = 32; o; o >>= 1) {
            float d2 = __shfl_xor(bd, o);
            int   i2 = __shfl_xor(bi_, o);
            if (d2 < bd || (d2 == bd && i2 < bi_)) { bd = d2; bi_ = i2; }
        }
        if (lane == j) mynb = bi_;
        if ((bi_ & 63) == lane) msk |= 1u << (bi_ >> 6);
    }

    // --- own tq (uniform across wave, te[t] from LDS broadcast) ---
    float tq[NH];
    #pragma unroll
    for (int h = 0; h < NH; ++h) {
        float a = b_V[h];
        #pragma unroll
        for (int j = 0; j < NH; ++j) a += s_te[t][j] * W_V[j * NH + h];
        tq[h] = a;
    }
    float wat[NH];
    #pragma unroll
    for (int h = 0; h < NH; ++h) wat[h] = W_at[h];
    float bat = b_at[0];

    // --- phase 2: neighbor scoring from LDS (lanes 0-8 meaningful) ---
    float tej[NH];
    #pragma unroll
    for (int h = 0; h < NH; ++h) tej[h] = s_te[mynb][h];
    float sc2 = bat;
    #pragma unroll
    for (int h = 0; h < NH; ++h) sc2 += ft(tq[h] + s_tk[mynb][h]) * wat[h];

    float a2 = (lane < KNN) ? sc2 : -3.0e38f;
    float vm = a2;
    #pragma unroll
    for (int o = 8; o; o >>= 1) vm = fmaxf(vm, __shfl_xor(vm, o));
    float p2 = (lane < KNN) ? __expf(a2 - vm) : 0.f;
    float ss = p2;
    #pragma unroll
    for (int o = 8; o; o >>= 1) ss += __shfl_xor(ss, o);
    float aggT[NH];
    #pragma unroll
    for (int h = 0; h < NH; ++h) {
        float v = p2 * tej[h];
        #pragma unroll
        for (int o = 8; o; o >>= 1) v += __shfl_xor(v, o);
        aggT[h] = v;
    }

    // --- phase 3: u-softmax, lane = u, up/uk from LDS ---
    float up[NH];
    #pragma unroll
    for (int h = 0; h < NH; ++h) up[h] = s_up[lane][h];
    float au = bat;
    #pragma unroll
    for (int h = 0; h < NH; ++h) au += ft(s_uk[lane][h] + tq[h]) * wat[h];
    float um = au;
    #pragma unroll
    for (int o = 32; o; o >>= 1) um = fmaxf(um, __shfl_xor(um, o));
    float pu = __expf(au - um);
    float su = pu;
    #pragma unroll
    for (int o = 32; o; o >>= 1) su += __shfl_xor(su, o);
    float aggU[NH];
    #pragma unroll
    for (int h = 0; h < NH; ++h) {
        float v = pu * up[h];
        #pragma unroll
        for (int o = 32; o; o >>= 1) v += __shfl_xor(v, o);
        aggU[h] = v;
    }

    // --- finalize on lanes 0-7 (h = lane); static-index selection ---
    float tqh = tq[0], teh = s_te[t][0], aT = aggT[0], aU = aggU[0];
    #pragma unroll
    for (int h = 1; h < NH; ++h)
        if (lane == h) { tqh = tq[h]; teh = s_te[t][h]; aT = aggT[h]; aU = aggU[h]; }
    if (lane < NH) {
        float invT = 1.f / ss, invU = 1.f / su;
        float sig = 1.f / (1.f + __expf(-tqh));
        float x = sig * teh + aT * invT + aU * invU;
        float r = x > 0.f ? x : __expf(x) - 1.f;
        out_task[(b * NT + t) * NH + lane] = r;
    }
}

extern "C" void kernel_launch(void* const* d_in, const int* in_sizes, int n_in,
                              void* d_out, int out_size, void* d_ws, size_t ws_size,
                              hipStream_t stream)
{
    const float* usv_f  = (const float*)d_in[0];
    const float* task_f = (const float*)d_in[1];
    const int*   adj    = (const int*)  d_in[2];
    // d_in[3] edge_features: unused by the reference
    const float* W_usv  = (const float*)d_in[4];
    const float* b_usv  = (const float*)d_in[5];
    const float* W_task = (const float*)d_in[6];
    const float* b_task = (const float*)d_in[7];
    const float* W_au   = (const float*)d_in[8];
    const float* b_au   = (const float*)d_in[9];
    const float* W_at   = (const float*)d_in[10];
    const float* b_at   = (const float*)d_in[11];
    const float* W_Q    = (const float*)d_in[12];
    const float* b_Q    = (const float*)d_in[13];
    const float* W_K    = (const float*)d_in[14];
    const float* b_K    = (const float*)d_in[15];
    const float* W_V    = (const float*)d_in[16];
    const float* b_V    = (const float*)d_in[17];

    float* out_usv  = (float*)d_out;
    float* out_task = out_usv + NB * NU * NH;

    hipLaunchKernelGGL(k_usv, dim3(NB * NU), dim3(512), 0, stream,
                       usv_f, task_f, adj,
                       W_usv, b_usv, W_task, b_task, W_au, b_au,
                       W_Q, b_Q, W_K, b_K, out_usv);
    hipLaunchKernelGGL(k_task3, dim3(NB * 64), dim3(512), 0, stream,
                       task_f, W_task, b_task, W_K, b_K, W_V, b_V,
                       W_Q, b_Q, W_at, b_at, out_usv, out_task);
}

// Round 10
// 100.354 us; speedup vs baseline: 4.5308x; 1.4288x over previous
//
#include <hip/hip_runtime.h>
#include <hip/hip_bf16.h>

#define NB 64
#define NU 64
#define NT 512
#define NH 8
#define KNN 9
#define PAD 9
#define NEGV -1000000000.0f

// fast tanh via hardware exp: exact at saturation
__device__ __forceinline__ float ft(float x) {
    return 1.f - 2.f / (__expf(2.f * x) + 1.f);
}

// =====================================================================
// Kernel A: one block per (b,u), 512 threads, thread t owns task t.
// Round-9 structure; aggregation rebuilt as (g,h) LDS decomposition:
// thread (g=t>>3, h=t&7) accumulates 8 partial FMAs, xor-reduce over g.
// =====================================================================
__global__ void __launch_bounds__(512) k_usv(
    const float* __restrict__ usv_f, const float* __restrict__ task_f,
    const int* __restrict__ adj,
    const float* __restrict__ W_usv, const float* __restrict__ b_usv,
    const float* __restrict__ W_task, const float* __restrict__ b_task,
    const float* __restrict__ W_au, const float* __restrict__ b_au,
    const float* __restrict__ W_Q, const float* __restrict__ b_Q,
    const float* __restrict__ W_K, const float* __restrict__ b_K,
    float* __restrict__ out_usv)
{
    __shared__ float s_te2[NT][PAD];
    __shared__ float s_p[NT];
    __shared__ float s_max[8];
    __shared__ float s_sum[8];
    __shared__ float s_wp[8][NH];

    const int b = blockIdx.x >> 6;     // blockIdx.x = b*NU + u
    const int u = blockIdx.x & 63;
    const int t = threadIdx.x;
    const int lane = t & 63, wv = t >> 6;

    float ue[NH], q[NH];
    {
        float f0 = usv_f[(b * NU + u) * 4 + 0];
        float f1 = usv_f[(b * NU + u) * 4 + 1];
        float f2 = usv_f[(b * NU + u) * 4 + 2];
        float f3 = usv_f[(b * NU + u) * 4 + 3];
        #pragma unroll
        for (int h = 0; h < NH; ++h)
            ue[h] = b_usv[h] + f0 * W_usv[0 * NH + h] + f1 * W_usv[1 * NH + h]
                             + f2 * W_usv[2 * NH + h] + f3 * W_usv[3 * NH + h];
        #pragma unroll
        for (int h = 0; h < NH; ++h) {
            float a = b_Q[h];
            #pragma unroll
            for (int j = 0; j < NH; ++j) a += ue[j] * W_Q[j * NH + h];
            q[h] = a;
        }
    }

    float te[NH], tk[NH];
    {
        float f[5];
        #pragma unroll
        for (int j = 0; j < 5; ++j) f[j] = task_f[(b * NT + t) * 5 + j];
        #pragma unroll
        for (int h = 0; h < NH; ++h) {
            float a = b_task[h];
            #pragma unroll
            for (int j = 0; j < 5; ++j) a += f[j] * W_task[j * NH + h];
            te[h] = a;
            s_te2[t][h] = a;
        }
        #pragma unroll
        for (int h = 0; h < NH; ++h) {
            float a = b_K[h];
            #pragma unroll
            for (int j = 0; j < NH; ++j) a += te[j] * W_K[j * NH + h];
            tk[h] = a;
        }
    }

    float sc = b_au[0];
    #pragma unroll
    for (int h = 0; h < NH; ++h) sc += ft(q[h] + tk[h]) * W_au[h];
    if (adj[(b * NU + u) * NT + t] == 0) sc = NEGV;

    float m = sc;
    #pragma unroll
    for (int o = 32; o; o >>= 1) m = fmaxf(m, __shfl_xor(m, o));
    if (lane == 0) s_max[wv] = m;
    __syncthreads();                      // also publishes s_te2
    float M = s_max[0];
    for (int w = 1; w < 8; ++w) M = fmaxf(M, s_max[w]);

    float p = __expf(sc - M);
    s_p[t] = p;
    float ps = p;
    #pragma unroll
    for (int o = 32; o; o >>= 1) ps += __shfl_xor(ps, o);
    if (lane == 0) s_sum[wv] = ps;
    __syncthreads();                      // publishes s_p

    // (g,h) partial aggregation: thread covers tasks g*8..g*8+7 for h=t&7
    const int g8 = (t >> 3) << 3;
    const int hh = t & 7;
    float part = 0.f;
    #pragma unroll
    for (int i = 0; i < 8; ++i)
        part += s_p[g8 + i] * s_te2[g8 + i][hh];
    part += __shfl_xor(part, 8);
    part += __shfl_xor(part, 16);
    part += __shfl_xor(part, 32);
    if (lane < NH) s_wp[wv][lane] = part;   // lane<8 -> hh==lane
    __syncthreads();

    if (t < NH) {
        float PS = 0.f;
        #pragma unroll
        for (int w = 0; w < 8; ++w) PS += s_sum[w];
        float A = 0.f;
        #pragma unroll
        for (int w = 0; w < 8; ++w) A += s_wp[w][t];
        float qh = q[0], ueh = ue[0];
        #pragma unroll
        for (int h = 1; h < NH; ++h) if (t == h) { qh = q[h]; ueh = ue[h]; }
        float sig = 1.f / (1.f + __expf(-qh));
        float x = sig * ueh + A / PS;
        float upd = x > 0.f ? x : __expf(x) - 1.f;
        out_usv[(b * NU + u) * NH + t] = upd;
    }
}

// =====================================================================
// Kernel B: LDS-staged wave-per-task (round-9 structure) with
// (1) u64-packed kNN keys (bits(d)<<32 | idx; exact lex semantics),
// (2) LDS-based aggT (serial-9 on lanes 0-7),
// (3) (g,h) LDS decomposition for aggU.
// =====================================================================
__global__ void __launch_bounds__(512) k_task4(
    const float* __restrict__ task_f,
    const float* __restrict__ W_task, const float* __restrict__ b_task,
    const float* __restrict__ W_K, const float* __restrict__ b_K,
    const float* __restrict__ W_V, const float* __restrict__ b_V,
    const float* __restrict__ W_Q, const float* __restrict__ b_Q,
    const float* __restrict__ W_at, const float* __restrict__ b_at,
    const float* __restrict__ out_usv,
    float* __restrict__ out_task)
{
    __shared__ float s_cx[NT], s_cy[NT];
    __shared__ float s_te[NT][PAD];
    __shared__ float s_tk[NT][PAD];
    __shared__ float s_up[NU][PAD];
    __shared__ float s_uk[NU][PAD];
    __shared__ float s_p2[8][12];
    __shared__ int   s_nb[8][12];
    __shared__ float s_pu[8][NU];

    const int b    = blockIdx.x >> 6;
    const int tile = blockIdx.x & 63;
    const int wid  = threadIdx.x >> 6;
    const int lane = threadIdx.x & 63;
    const int t    = tile * 8 + wid;

    // --- staging: thread i computes te/tk/coords for task i ---
    {
        int i = threadIdx.x;
        float f[5];
        #pragma unroll
        for (int j = 0; j < 5; ++j) f[j] = task_f[(b * NT + i) * 5 + j];
        s_cx[i] = f[0]; s_cy[i] = f[1];
        float e[NH];
        #pragma unroll
        for (int h = 0; h < NH; ++h) {
            float a = b_task[h];
            #pragma unroll
            for (int j = 0; j < 5; ++j) a += f[j] * W_task[j * NH + h];
            e[h] = a;
            s_te[i][h] = a;
        }
        #pragma unroll
        for (int h = 0; h < NH; ++h) {
            float a = b_K[h];
            #pragma unroll
            for (int j = 0; j < NH; ++j) a += e[j] * W_K[j * NH + h];
            s_tk[i][h] = a;
        }
    }
    if (threadIdx.x < NU) {
        int u = threadIdx.x;
        float up[NH];
        #pragma unroll
        for (int h = 0; h < NH; ++h) {
            up[h] = out_usv[(b * NU + u) * NH + h];
            s_up[u][h] = up[h];
        }
        #pragma unroll
        for (int h = 0; h < NH; ++h) {
            float a = b_Q[h];
            #pragma unroll
            for (int j = 0; j < NH; ++j) a += up[j] * W_Q[j * NH + h];
            s_uk[u][h] = a;
        }
    }
    __syncthreads();

    // --- phase 1: u64-key kNN, 9-round lex-min extraction ---
    float mx = s_cx[t], my = s_cy[t];
    unsigned long long kl[8];
    #pragma unroll
    for (int i = 0; i < 8; ++i) {
        int s = i * 64 + lane;
        float dx = mx - s_cx[s], dy = my - s_cy[s];
        float d = sqrtf(dx * dx + dy * dy);
        kl[i] = ((unsigned long long)__float_as_uint(d) << 32) | (unsigned)s;
    }
    int mynb = t;
    #pragma unroll
    for (int j = 0; j < KNN; ++j) {
        unsigned long long bk = kl[0];
        #pragma unroll
        for (int i = 1; i < 8; ++i) bk = (kl[i] < bk) ? kl[i] : bk;
        #pragma unroll
        for (int o = 32; o; o >>= 1) {
            unsigned long long k2 = __shfl_xor(bk, o);
            bk = (k2 < bk) ? k2 : bk;
        }
        if (lane == j) mynb = (int)(bk & 511ULL);
        unsigned sw = (unsigned)bk;          // low 32 bits = candidate idx
        if ((sw & 63u) == (unsigned)lane) {
            int slot = (int)(sw >> 6) & 7;
            #pragma unroll
            for (int i = 0; i < 8; ++i) if (i == slot) kl[i] = ~0ULL;
        }
    }

    // --- own tq (uniform across wave) ---
    float tq[NH];
    #pragma unroll
    for (int h = 0; h < NH; ++h) {
        float a = b_V[h];
        #pragma unroll
        for (int j = 0; j < NH; ++j) a += s_te[t][j] * W_V[j * NH + h];
        tq[h] = a;
    }
    float wat[NH];
    #pragma unroll
    for (int h = 0; h < NH; ++h) wat[h] = W_at[h];
    float bat = b_at[0];

    // --- phase 2: neighbor scoring (lanes 0-8 meaningful) ---
    float sc2 = bat;
    #pragma unroll
    for (int h = 0; h < NH; ++h) sc2 += ft(tq[h] + s_tk[mynb][h]) * wat[h];
    float a2 = (lane < KNN) ? sc2 : -3.0e38f;
    float vm = a2;
    #pragma unroll
    for (int o = 8; o; o >>= 1) vm = fmaxf(vm, __shfl_xor(vm, o));
    float p2 = (lane < KNN) ? __expf(a2 - vm) : 0.f;
    float ss = p2;
    #pragma unroll
    for (int o = 8; o; o >>= 1) ss += __shfl_xor(ss, o);
    if (lane < KNN) { s_p2[wid][lane] = p2; s_nb[wid][lane] = mynb; }
    // wave-local LDS exchange: same-wave ds_write -> ds_read, in-order
    float aT = 0.f;
    if (lane < NH) {
        #pragma unroll
        for (int j2 = 0; j2 < KNN; ++j2)
            aT += s_p2[wid][j2] * s_te[s_nb[wid][j2]][lane];
    }

    // --- phase 3: u-softmax, lane = u; aggU via (g,h) decomposition ---
    float au = bat;
    #pragma unroll
    for (int h = 0; h < NH; ++h) au += ft(s_uk[lane][h] + tq[h]) * wat[h];
    float um = au;
    #pragma unroll
    for (int o = 32; o; o >>= 1) um = fmaxf(um, __shfl_xor(um, o));
    float pu = __expf(au - um);
    float su = pu;
    #pragma unroll
    for (int o = 32; o; o >>= 1) su += __shfl_xor(su, o);
    s_pu[wid][lane] = pu;
    const int gb = (lane >> 3) << 3;
    const int hh = lane & 7;
    float aU = 0.f;
    #pragma unroll
    for (int i = 0; i < 8; ++i)
        aU += s_pu[wid][gb + i] * s_up[gb + i][hh];
    aU += __shfl_xor(aU, 8);
    aU += __shfl_xor(aU, 16);
    aU += __shfl_xor(aU, 32);

    // --- finalize on lanes 0-7 (h = lane) ---
    if (lane < NH) {
        float tqh = tq[0];
        #pragma unroll
        for (int h = 1; h < NH; ++h) if (lane == h) tqh = tq[h];
        float invT = 1.f / ss, invU = 1.f / su;
        float sig = 1.f / (1.f + __expf(-tqh));
        float x = sig * s_te[t][lane] + aT * invT + aU * invU;
        float r = x > 0.f ? x : __expf(x) - 1.f;
        out_task[(b * NT + t) * NH + lane] = r;
    }
}

extern "C" void kernel_launch(void* const* d_in, const int* in_sizes, int n_in,
                              void* d_out, int out_size, void* d_ws, size_t ws_size,
                              hipStream_t stream)
{
    const float* usv_f  = (const float*)d_in[0];
    const float* task_f = (const float*)d_in[1];
    const int*   adj    = (const int*)  d_in[2];
    // d_in[3] edge_features: unused by the reference
    const float* W_usv  = (const float*)d_in[4];
    const float* b_usv  = (const float*)d_in[5];
    const float* W_task = (const float*)d_in[6];
    const float* b_task = (const float*)d_in[7];
    const float* W_au   = (const float*)d_in[8];
    const float* b_au   = (const float*)d_in[9];
    const float* W_at   = (const float*)d_in[10];
    const float* b_at   = (const float*)d_in[11];
    const float* W_Q    = (const float*)d_in[12];
    const float* b_Q    = (const float*)d_in[13];
    const float* W_K    = (const float*)d_in[14];
    const float* b_K    = (const float*)d_in[15];
    const float* W_V    = (const float*)d_in[16];
    const float* b_V    = (const float*)d_in[17];

    float* out_usv  = (float*)d_out;
    float* out_task = out_usv + NB * NU * NH;

    hipLaunchKernelGGL(k_usv, dim3(NB * NU), dim3(512), 0, stream,
                       usv_f, task_f, adj,
                       W_usv, b_usv, W_task, b_task, W_au, b_au,
                       W_Q, b_Q, W_K, b_K, out_usv);
    hipLaunchKernelGGL(k_task4, dim3(NB * 64), dim3(512), 0, stream,
                       task_f, W_task, b_task, W_K, b_K, W_V, b_V,
                       W_Q, b_Q, W_at, b_at, out_usv, out_task);
}